// Round 8
// baseline (273.508 us; speedup 1.0000x reference)
//
#include <hip/hip_runtime.h>
#include <hip/hip_cooperative_groups.h>

namespace cg = cooperative_groups;

// HandcraftedPodExtractor: 3D cell binning + normalized feature vector.
// Input  x: (64, 65536, 6) fp32  [pos(3) | ori(3)] interleaved per point.
// Output  : (64, 640) fp32.
//
// R7 post-mortem: fused cooperative kernel produced garbage — consistent
// with hipLaunchCooperativeKernel REJECTING the 1024-block grid (return
// code was unchecked; acc stayed poisoned). R8: same fused kernel, but
// the launch's error code is checked and on failure we fall back to the
// proven R6 two-kernel path. Deterministic per-environment => identical
// work every call => graph-capture legal. dur_us tells us which path ran
// (~148 fused vs ~162 fallback).
//
// Fixed-point scales (R3):
//   offsets: round(off * 2^18); cov: round(v * 2^12); err ~1e-4 << 5.9e-3.
// Bank swizzle (R6): k' = k ^ (cell & 15) on stride-16 copies.
//
// ws layout:
//   [0,    4096)           : part_max[B*16] as uint bits (nonneg floats)
//   [4096, 4096 + 327680)  : acc[B][640] int64

#define BATCH 64
#define NPTS 65536
#define FEAT 640          // 64 cells * 10 values
#define COPIES 16         // replicated LDS histograms, XOR-swizzled
#define CSTRIDE 16        // copy stride (no pad; swizzle handles banks)
#define S_OFF 262144.0f   // 2^18
#define S_COV 4096.0f     // 2^12

__device__ __forceinline__ void bin_point(int* h, int k,
                                          float px, float py, float pz,
                                          float ox, float oy, float oz,
                                          float bmax, float inv_thick) {
    float sx = (px + bmax) * inv_thick;
    float sy = (py + bmax) * inv_thick;
    float sz = (pz + bmax) * inv_thick;
    int cx = (int)(sx * 4.0f); cx = cx < 0 ? 0 : (cx > 3 ? 3 : cx);
    int cy = (int)(sy * 4.0f); cy = cy < 0 ? 0 : (cy > 3 ? 3 : cy);
    int cz = (int)(sz * 4.0f); cz = cz < 0 ? 0 : (cz > 3 ? 3 : cz);
    int cell = (cx * 4 + cy) * 4 + cz;
    float offx = sx - (cx * 0.25f + 0.125f);
    float offy = sy - (cy * 0.25f + 0.125f);
    float offz = sz - (cz * 0.25f + 0.125f);
    int kk = k ^ (cell & 15);               // bank de-alias across cells
    int a = cell * (10 * CSTRIDE) + kk;
    atomicAdd(&h[a + 0 * CSTRIDE], 1);
    atomicAdd(&h[a + 1 * CSTRIDE], __float2int_rn(offx * S_OFF));
    atomicAdd(&h[a + 2 * CSTRIDE], __float2int_rn(offy * S_OFF));
    atomicAdd(&h[a + 3 * CSTRIDE], __float2int_rn(offz * S_OFF));
    atomicAdd(&h[a + 4 * CSTRIDE], __float2int_rn(ox * ox * S_COV));
    atomicAdd(&h[a + 5 * CSTRIDE], __float2int_rn(ox * oy * S_COV));
    atomicAdd(&h[a + 6 * CSTRIDE], __float2int_rn(ox * oz * S_COV));
    atomicAdd(&h[a + 7 * CSTRIDE], __float2int_rn(oy * oy * S_COV));
    atomicAdd(&h[a + 8 * CSTRIDE], __float2int_rn(oy * oz * S_COV));
    atomicAdd(&h[a + 9 * CSTRIDE], __float2int_rn(oz * oz * S_COV));
}

// ---------------- fused path (cooperative) ----------------
// grid (16, B) x 256. One HBM pass; points held in 24 float4 regs across
// the grid barrier. LDS 40960 B -> 4 blocks/CU; launch_bounds caps VGPR 128.
__global__ __launch_bounds__(256, 4)
void k_fused(const float* __restrict__ x,
             unsigned int* __restrict__ part,
             unsigned long long* __restrict__ acc) {
    __shared__ int h[FEAT * CSTRIDE];
    int b = blockIdx.y;
    int fb = b * 16 + blockIdx.x;             // flat block id 0..1023
    int t = threadIdx.x;

    const float4* base = (const float4*)(x + (size_t)b * NPTS * 6);
    int tid = blockIdx.x * 256 + t;           // 4096 threads per batch
    float4 d[24];
    #pragma unroll
    for (int it = 0; it < 8; ++it) {
        int i = tid + it * 4096;              // pair index < 32768
        d[it * 3 + 0] = base[3 * i + 0];
        d[it * 3 + 1] = base[3 * i + 1];
        d[it * 3 + 2] = base[3 * i + 2];
    }
    if (t < 40) acc[fb * 40 + t] = 0ULL;      // zero acc slice

    float m = 0.0f;
    #pragma unroll
    for (int it = 0; it < 8; ++it) {
        float4 f0 = d[it * 3 + 0], f1 = d[it * 3 + 1], f2 = d[it * 3 + 2];
        m = fmaxf(m, fabsf(f0.x)); m = fmaxf(m, fabsf(f0.y)); m = fmaxf(m, fabsf(f0.z));
        m = fmaxf(m, fabsf(f1.z)); m = fmaxf(m, fabsf(f1.w)); m = fmaxf(m, fabsf(f2.x));
    }
    for (int off = 32; off > 0; off >>= 1) m = fmaxf(m, __shfl_down(m, off, 64));
    if ((t & 63) == 0) h[t >> 6] = __float_as_int(m);   // reuse h pre-zero
    __syncthreads();
    if (t == 0) {
        float bm = fmaxf(fmaxf(__int_as_float(h[0]), __int_as_float(h[1])),
                         fmaxf(__int_as_float(h[2]), __int_as_float(h[3])));
        part[fb] = __float_as_uint(bm);
    }
    __syncthreads();
    for (int i = t; i < FEAT * CSTRIDE; i += 256) h[i] = 0;

    cg::this_grid().sync();                   // partial maxes + zeros visible

    unsigned int um = 0u;
    #pragma unroll
    for (int p = 0; p < 16; ++p) um = um > part[b * 16 + p] ? um : part[b * 16 + p];
    float bmax = __uint_as_float(um);
    float thick = fmaxf(2.0f * bmax, 1e-5f);
    float inv_thick = 1.0f / thick;

    int k = t & (COPIES - 1);
    #pragma unroll
    for (int it = 0; it < 8; ++it) {
        float4 f0 = d[it * 3 + 0], f1 = d[it * 3 + 1], f2 = d[it * 3 + 2];
        bin_point(h, k, f0.x, f0.y, f0.z, f0.w, f1.x, f1.y, bmax, inv_thick);
        bin_point(h, k, f1.z, f1.w, f2.x, f2.y, f2.z, f2.w, bmax, inv_thick);
    }
    __syncthreads();
    for (int v = t; v < FEAT; v += 256) {
        long long sum = 0;
        #pragma unroll
        for (int c = 0; c < COPIES; ++c) sum += (long long)h[v * CSTRIDE + c];
        atomicAdd(&acc[b * FEAT + v], (unsigned long long)sum);
    }
}

// ---------------- fallback path (proven R6) ----------------
__global__ __launch_bounds__(256) void k_bbox(const float* __restrict__ x,
                                              unsigned int* __restrict__ part,
                                              unsigned long long* __restrict__ acc) {
    int b = blockIdx.y;
    int fb = b * 16 + blockIdx.x;
    if (threadIdx.x < 40) acc[fb * 40 + threadIdx.x] = 0ULL;

    const float4* F = (const float4*)(x + (size_t)b * NPTS * 6);
    int tid = blockIdx.x * 256 + threadIdx.x;
    int tm = tid % 3;
    float m = 0.0f;
    #pragma unroll
    for (int o = 0; o < 2; ++o) {
        #pragma unroll
        for (int u = 0; u < 12; ++u) {
            int it = o * 12 + u;
            float4 v = F[tid + it * 4096];
            int mm = tm + (u % 3);
            mm = mm >= 3 ? mm - 3 : mm;
            float ax = fabsf(v.x), ay = fabsf(v.y), az = fabsf(v.z), aw = fabsf(v.w);
            float c0 = fmaxf(fmaxf(ax, ay), az);
            float c1 = fmaxf(az, aw);
            float cand = mm == 0 ? c0 : (mm == 1 ? c1 : ax);
            m = fmaxf(m, cand);
        }
    }
    for (int off = 32; off > 0; off >>= 1) m = fmaxf(m, __shfl_down(m, off, 64));
    __shared__ float s[4];
    if ((threadIdx.x & 63) == 0) s[threadIdx.x >> 6] = m;
    __syncthreads();
    if (threadIdx.x == 0) {
        m = fmaxf(fmaxf(s[0], s[1]), fmaxf(s[2], s[3]));
        part[fb] = __float_as_uint(m);
    }
}

__global__ __launch_bounds__(256) void k_bin(const float* __restrict__ x,
                                             const unsigned int* __restrict__ part,
                                             unsigned long long* __restrict__ acc) {
    __shared__ int h[FEAT * CSTRIDE];
    for (int i = threadIdx.x; i < FEAT * CSTRIDE; i += 256) h[i] = 0;
    int b = blockIdx.y;
    unsigned int um = 0u;
    #pragma unroll
    for (int p = 0; p < 16; ++p) um = um > part[b * 16 + p] ? um : part[b * 16 + p];
    float bmax = __uint_as_float(um);
    float thick = fmaxf(2.0f * bmax, 1e-5f);
    float inv_thick = 1.0f / thick;
    __syncthreads();

    const float4* base = (const float4*)(x + (size_t)b * NPTS * 6);
    int tid = blockIdx.x * 256 + threadIdx.x;
    int k = threadIdx.x & (COPIES - 1);
    #pragma unroll
    for (int it = 0; it < 8; ++it) {
        int i = tid + it * 4096;
        float4 f0 = base[3 * i + 0];
        float4 f1 = base[3 * i + 1];
        float4 f2 = base[3 * i + 2];
        bin_point(h, k, f0.x, f0.y, f0.z, f0.w, f1.x, f1.y, bmax, inv_thick);
        bin_point(h, k, f1.z, f1.w, f2.x, f2.y, f2.z, f2.w, bmax, inv_thick);
    }
    __syncthreads();
    for (int v = threadIdx.x; v < FEAT; v += 256) {
        long long sum = 0;
        #pragma unroll
        for (int c = 0; c < COPIES; ++c) sum += (long long)h[v * CSTRIDE + c];
        atomicAdd(&acc[b * FEAT + v], (unsigned long long)sum);
    }
}

// Features + L2 normalize. grid B x 640 (one thread per feature).
__global__ __launch_bounds__(640) void k_final(const unsigned long long* __restrict__ acc,
                                               float* __restrict__ out) {
    int b = blockIdx.x;
    int t = threadIdx.x;           // 0..639
    int cell = t / 10, j = t - cell * 10;
    long long ni = (long long)acc[b * FEAT + cell * 10];   // exact count
    long long vi = (long long)acc[b * FEAT + t];
    float n = (float)ni;
    float fc = fmaxf(n, 1.0f);
    float up = 1.0f / sqrtf(fc);
    float val;
    if (j == 0)      val = 0.001f * n * up;
    else if (j < 4)  val = ((float)vi * (1.0f / S_OFF)) * up;
    else             val = ((float)vi * (1.0f / S_COV)) / fc;

    __shared__ float red[12];
    float s = val * val;
    for (int off = 32; off > 0; off >>= 1) s += __shfl_down(s, off, 64);
    if ((t & 63) == 0) red[t >> 6] = s;
    __syncthreads();
    if (t == 0) {
        float tot = 0.0f;
        #pragma unroll
        for (int w = 0; w < 10; ++w) tot += red[w];
        red[10] = fmaxf(sqrtf(tot), 1e-12f);
    }
    __syncthreads();
    out[b * FEAT + t] = val / red[10];
}

extern "C" void kernel_launch(void* const* d_in, const int* in_sizes, int n_in,
                              void* d_out, int out_size, void* d_ws, size_t ws_size,
                              hipStream_t stream) {
    const float* x = (const float*)d_in[0];
    float* out = (float*)d_out;
    unsigned int* part = (unsigned int*)d_ws;
    unsigned long long* acc = (unsigned long long*)((char*)d_ws + 4096);

    // Try the fused cooperative path; on launch rejection (capacity /
    // capture compat), fall back to the proven two-kernel path. The
    // outcome is deterministic per environment => same work every call.
    void* args[] = { (void*)&x, (void*)&part, (void*)&acc };
    hipError_t err = hipLaunchCooperativeKernel((void*)k_fused,
                                                dim3(16, BATCH), dim3(256),
                                                args, 0, stream);
    if (err != hipSuccess) {
        dim3 grid(16, BATCH);
        k_bbox<<<grid, 256, 0, stream>>>(x, part, acc);
        k_bin<<<grid, 256, 0, stream>>>(x, part, acc);
    }
    k_final<<<BATCH, 640, 0, stream>>>(acc, out);
}

// Round 9
// 188.556 us; speedup vs baseline: 1.4505x; 1.4505x over previous
//
#include <hip/hip_runtime.h>

// HandcraftedPodExtractor: 3D cell binning + normalized feature vector.
// Input  x: (64, 65536, 6) fp32  [pos(3) | ori(3)] interleaved per point.
// Output  : (64, 640) fp32.
//
// R8 post-mortem: cooperative fusion ran at 149.8us alone (VGPR=60 ->
// compiler would not hold points in regs across grid.sync; barrier is a
// device-scope spin across 8 non-coherent XCD L2s) and was racy (R7 fail /
// R8 pass, same code). REVERTED to the proven two-kernel path.
// R9: fold k_final into k_bin via the last-block pattern: release-scoped
// done-counter; 16th block of each batch re-reads acc with device-scope
// atomic loads and does the normalize+store. Saves one dispatch + gap.
// LDS stays exactly 40960 B (flag/scratch reuse h[]) -> 4 blocks/CU.
//
// Fixed-point scales (R3): offsets x2^18, cov x2^12; out err ~1e-4 << 5.9e-3.
// Bank swizzle (R6): k' = k ^ (cell & 15) on stride-16 copies (4 blk/CU
// beats the half-space bank conflicts it introduces — R5->R6 measured).
//
// ws layout:
//   [0,    4096)           : part_max[B*16] as uint bits (nonneg floats)
//   [4096, 8192)           : done[B] counters (int)
//   [8192, 8192 + 327680)  : acc[B][640] int64

#define BATCH 64
#define NPTS 65536
#define FEAT 640          // 64 cells * 10 values
#define COPIES 16         // replicated LDS histograms, XOR-swizzled
#define CSTRIDE 16        // copy stride (no pad; swizzle handles banks)
#define S_OFF 262144.0f   // 2^18
#define S_COV 4096.0f     // 2^12

__device__ __forceinline__ void bin_point(int* h, int k,
                                          float px, float py, float pz,
                                          float ox, float oy, float oz,
                                          float bmax, float inv_thick) {
    float sx = (px + bmax) * inv_thick;
    float sy = (py + bmax) * inv_thick;
    float sz = (pz + bmax) * inv_thick;
    int cx = (int)(sx * 4.0f); cx = cx < 0 ? 0 : (cx > 3 ? 3 : cx);
    int cy = (int)(sy * 4.0f); cy = cy < 0 ? 0 : (cy > 3 ? 3 : cy);
    int cz = (int)(sz * 4.0f); cz = cz < 0 ? 0 : (cz > 3 ? 3 : cz);
    int cell = (cx * 4 + cy) * 4 + cz;
    float offx = sx - (cx * 0.25f + 0.125f);
    float offy = sy - (cy * 0.25f + 0.125f);
    float offz = sz - (cz * 0.25f + 0.125f);
    int kk = k ^ (cell & 15);               // bank de-alias across cells
    int a = cell * (10 * CSTRIDE) + kk;
    atomicAdd(&h[a + 0 * CSTRIDE], 1);
    atomicAdd(&h[a + 1 * CSTRIDE], __float2int_rn(offx * S_OFF));
    atomicAdd(&h[a + 2 * CSTRIDE], __float2int_rn(offy * S_OFF));
    atomicAdd(&h[a + 3 * CSTRIDE], __float2int_rn(offz * S_OFF));
    atomicAdd(&h[a + 4 * CSTRIDE], __float2int_rn(ox * ox * S_COV));
    atomicAdd(&h[a + 5 * CSTRIDE], __float2int_rn(ox * oy * S_COV));
    atomicAdd(&h[a + 6 * CSTRIDE], __float2int_rn(ox * oz * S_COV));
    atomicAdd(&h[a + 7 * CSTRIDE], __float2int_rn(oy * oy * S_COV));
    atomicAdd(&h[a + 8 * CSTRIDE], __float2int_rn(oy * oz * S_COV));
    atomicAdd(&h[a + 9 * CSTRIDE], __float2int_rn(oz * oz * S_COV));
}

// Pass 1: per-batch max|pos| -> partial maxes; zero acc + done counters.
// grid (16, B) x 256.
__global__ __launch_bounds__(256) void k_bbox(const float* __restrict__ x,
                                              unsigned int* __restrict__ part,
                                              int* __restrict__ done,
                                              unsigned long long* __restrict__ acc) {
    int b = blockIdx.y;
    int fb = b * 16 + blockIdx.x;             // flat block id 0..1023
    if (threadIdx.x < 40) acc[fb * 40 + threadIdx.x] = 0ULL;
    if (blockIdx.x == 0 && threadIdx.x == 64) done[b] = 0;

    const float4* base = (const float4*)(x + (size_t)b * NPTS * 6);
    int tid = blockIdx.x * 256 + threadIdx.x;   // 4096 threads per batch
    float m = 0.0f;
    #pragma unroll
    for (int it = 0; it < 8; ++it) {
        int i = tid + it * 4096;                // pair index < 32768
        float4 f0 = base[3 * i + 0];
        float4 f1 = base[3 * i + 1];
        float4 f2 = base[3 * i + 2];
        m = fmaxf(m, fabsf(f0.x)); m = fmaxf(m, fabsf(f0.y)); m = fmaxf(m, fabsf(f0.z));
        m = fmaxf(m, fabsf(f1.z)); m = fmaxf(m, fabsf(f1.w)); m = fmaxf(m, fabsf(f2.x));
    }
    for (int off = 32; off > 0; off >>= 1) m = fmaxf(m, __shfl_down(m, off, 64));
    __shared__ float s[4];
    if ((threadIdx.x & 63) == 0) s[threadIdx.x >> 6] = m;
    __syncthreads();
    if (threadIdx.x == 0) {
        m = fmaxf(fmaxf(s[0], s[1]), fmaxf(s[2], s[3]));
        part[fb] = __float_as_uint(m);
    }
}

// Pass 2: histogram + flush + (last block per batch) finalize.
// grid (16, B) x 256. LDS = 640*16*4 = 40960 B exactly -> 4 blocks/CU.
__global__ __launch_bounds__(256) void k_bin(const float* __restrict__ x,
                                             const unsigned int* __restrict__ part,
                                             int* __restrict__ done,
                                             unsigned long long* __restrict__ acc,
                                             float* __restrict__ out) {
    __shared__ int h[FEAT * CSTRIDE];
    float* hf = (float*)h;                      // scratch alias for finalize
    int t = threadIdx.x;
    for (int i = t; i < FEAT * CSTRIDE; i += 256) h[i] = 0;
    int b = blockIdx.y;
    unsigned int um = 0u;
    #pragma unroll
    for (int p = 0; p < 16; ++p) um = um > part[b * 16 + p] ? um : part[b * 16 + p];
    float bmax = __uint_as_float(um);
    float thick = fmaxf(2.0f * bmax, 1e-5f);
    float inv_thick = 1.0f / thick;
    __syncthreads();

    const float4* base = (const float4*)(x + (size_t)b * NPTS * 6);
    int tid = blockIdx.x * 256 + t;             // 4096 threads per batch
    int k = t & (COPIES - 1);
    #pragma unroll
    for (int it = 0; it < 8; ++it) {
        int i = tid + it * 4096;
        float4 f0 = base[3 * i + 0];
        float4 f1 = base[3 * i + 1];
        float4 f2 = base[3 * i + 2];
        bin_point(h, k, f0.x, f0.y, f0.z, f0.w, f1.x, f1.y, bmax, inv_thick);
        bin_point(h, k, f1.z, f1.w, f2.x, f2.y, f2.z, f2.w, bmax, inv_thick);
    }
    __syncthreads();
    for (int v = t; v < FEAT; v += 256) {
        long long sum = 0;
        #pragma unroll
        for (int c = 0; c < COPIES; ++c) sum += (long long)h[v * CSTRIDE + c];
        atomicAdd(&acc[b * FEAT + v], (unsigned long long)sum); // agent scope
    }
    __syncthreads();                            // all flush atomics issued; h reusable

    // ---- last-block-done finalize ----
    if (t == 0) {
        // release: prior atomics visible before counter bump
        int old = __hip_atomic_fetch_add(&done[b], 1, __ATOMIC_ACQ_REL,
                                         __HIP_MEMORY_SCOPE_AGENT);
        h[0] = (old == 15) ? 1 : 0;
    }
    __syncthreads();
    if (h[0] == 0) return;                      // not the last block
    __syncthreads();                            // h[0] consumed; reuse h as hf

    // device-scope atomic loads: correct across non-coherent XCD L2s
    float sq = 0.0f;
    float vals[3];
    #pragma unroll
    for (int r = 0; r < 3; ++r) {
        int v = t + r * 256;
        float val = 0.0f;
        if (v < FEAT) {
            int cell = v / 10, j = v - cell * 10;
            unsigned long long nu = __hip_atomic_load(&acc[b * FEAT + cell * 10],
                                                      __ATOMIC_RELAXED,
                                                      __HIP_MEMORY_SCOPE_AGENT);
            unsigned long long vu = __hip_atomic_load(&acc[b * FEAT + v],
                                                      __ATOMIC_RELAXED,
                                                      __HIP_MEMORY_SCOPE_AGENT);
            float n = (float)(long long)nu;
            float fc = fmaxf(n, 1.0f);
            float up = 1.0f / sqrtf(fc);
            if (j == 0)      val = 0.001f * n * up;
            else if (j < 4)  val = ((float)(long long)vu * (1.0f / S_OFF)) * up;
            else             val = ((float)(long long)vu * (1.0f / S_COV)) / fc;
            sq += val * val;
        }
        vals[r] = val;
    }
    // block reduction of sum(val^2) across 4 waves
    for (int off = 32; off > 0; off >>= 1) sq += __shfl_down(sq, off, 64);
    if ((t & 63) == 0) hf[1024 + (t >> 6)] = sq;
    __syncthreads();
    if (t == 0) {
        float tot = hf[1024] + hf[1025] + hf[1026] + hf[1027];
        hf[1028] = fmaxf(sqrtf(tot), 1e-12f);
    }
    __syncthreads();
    float norm = hf[1028];
    #pragma unroll
    for (int r = 0; r < 3; ++r) {
        int v = t + r * 256;
        if (v < FEAT) out[b * FEAT + v] = vals[r] / norm;
    }
}

extern "C" void kernel_launch(void* const* d_in, const int* in_sizes, int n_in,
                              void* d_out, int out_size, void* d_ws, size_t ws_size,
                              hipStream_t stream) {
    const float* x = (const float*)d_in[0];
    float* out = (float*)d_out;
    unsigned int* part = (unsigned int*)d_ws;
    int* done = (int*)((char*)d_ws + 4096);
    unsigned long long* acc = (unsigned long long*)((char*)d_ws + 8192);

    dim3 grid(16, BATCH);
    k_bbox<<<grid, 256, 0, stream>>>(x, part, done, acc);
    k_bin<<<grid, 256, 0, stream>>>(x, part, done, acc, out);
}

// Round 10
// 161.389 us; speedup vs baseline: 1.6947x; 1.1683x over previous
//
#include <hip/hip_runtime.h>

// HandcraftedPodExtractor: 3D cell binning + normalized feature vector.
// Input  x: (64, 65536, 6) fp32  [pos(3) | ori(3)] interleaved per point.
// Output  : (64, 640) fp32.
//
// R10 = exact revert to R6 (measured best: 162.1 us).
// History: R9 last-block fusion regressed (+26 us: finalize tail raised
// k_bin VGPR -> lost 4 blk/CU); R7/R8 cooperative fusion regressed
// (grid.sync = device-scope spin across 8 non-coherent XCD L2s, 149.8 us
// alone, and compiler refused to hold 96 VGPRs of points across it).
// The plain two-kernel pipeline wins: kernel-boundary barrier is cheap,
// occupancy + streaming dominate.
//
// Ceiling accounting (R9): ~107 us harness traffic in the timed window
// (402 MB ws-poison fill @ 59 us measured + ~48 us input restore) +
// k_bbox ~16 (HBM-bound) + k_bin ~20 (48 MB HBM + LDS atomics) +
// k_final ~4 + gaps ~10 = ~157 us vs 162 measured -> within ~4%.
//
// Fixed-point scales (R3): offsets x2^18, cov x2^12; out err ~1e-4 << 5.9e-3.
// Bank swizzle (R6): k' = k ^ (cell & 15) on stride-16 copies; LDS
// 640*16*4 = 40960 B exactly -> 4 blocks/CU (all 1024 blocks co-resident).
//
// ws layout:
//   [0,    4096)           : part_max[B*16] as uint bits (nonneg floats)
//   [4096, 4096 + 327680)  : acc[B][640] int64

#define BATCH 64
#define NPTS 65536
#define FEAT 640          // 64 cells * 10 values
#define COPIES 16         // replicated LDS histograms, XOR-swizzled
#define CSTRIDE 16        // copy stride (no pad; swizzle handles banks)
#define S_OFF 262144.0f   // 2^18
#define S_COV 4096.0f     // 2^12

__device__ __forceinline__ void bin_point(int* h, int k,
                                          float px, float py, float pz,
                                          float ox, float oy, float oz,
                                          float bmax, float inv_thick) {
    float sx = (px + bmax) * inv_thick;
    float sy = (py + bmax) * inv_thick;
    float sz = (pz + bmax) * inv_thick;
    int cx = (int)(sx * 4.0f); cx = cx < 0 ? 0 : (cx > 3 ? 3 : cx);
    int cy = (int)(sy * 4.0f); cy = cy < 0 ? 0 : (cy > 3 ? 3 : cy);
    int cz = (int)(sz * 4.0f); cz = cz < 0 ? 0 : (cz > 3 ? 3 : cz);
    int cell = (cx * 4 + cy) * 4 + cz;
    float offx = sx - (cx * 0.25f + 0.125f);
    float offy = sy - (cy * 0.25f + 0.125f);
    float offz = sz - (cz * 0.25f + 0.125f);
    int kk = k ^ (cell & 15);               // bank de-alias across cells
    int a = cell * (10 * CSTRIDE) + kk;
    atomicAdd(&h[a + 0 * CSTRIDE], 1);
    atomicAdd(&h[a + 1 * CSTRIDE], __float2int_rn(offx * S_OFF));
    atomicAdd(&h[a + 2 * CSTRIDE], __float2int_rn(offy * S_OFF));
    atomicAdd(&h[a + 3 * CSTRIDE], __float2int_rn(offz * S_OFF));
    atomicAdd(&h[a + 4 * CSTRIDE], __float2int_rn(ox * ox * S_COV));
    atomicAdd(&h[a + 5 * CSTRIDE], __float2int_rn(ox * oy * S_COV));
    atomicAdd(&h[a + 6 * CSTRIDE], __float2int_rn(ox * oz * S_COV));
    atomicAdd(&h[a + 7 * CSTRIDE], __float2int_rn(oy * oy * S_COV));
    atomicAdd(&h[a + 8 * CSTRIDE], __float2int_rn(oy * oz * S_COV));
    atomicAdd(&h[a + 9 * CSTRIDE], __float2int_rn(oz * oz * S_COV));
}

// Pass 1: per-batch max|pos| -> partial maxes; also zero-init acc.
// grid (16, B) x 256.
__global__ __launch_bounds__(256) void k_bbox(const float* __restrict__ x,
                                              unsigned int* __restrict__ part,
                                              unsigned long long* __restrict__ acc) {
    int b = blockIdx.y;
    int fb = b * 16 + blockIdx.x;             // flat block id 0..1023
    if (threadIdx.x < 40) acc[fb * 40 + threadIdx.x] = 0ULL;

    const float4* F = (const float4*)(x + (size_t)b * NPTS * 6);
    int tid = blockIdx.x * 256 + threadIdx.x;   // 4096 threads per batch
    int tm = tid % 3;
    float m = 0.0f;
    #pragma unroll
    for (int o = 0; o < 2; ++o) {
        #pragma unroll
        for (int u = 0; u < 12; ++u) {
            int it = o * 12 + u;
            float4 v = F[tid + it * 4096];      // unit stride across lanes
            int mm = tm + (u % 3);              // (tm + it) % 3; 12 % 3 == 0
            mm = mm >= 3 ? mm - 3 : mm;
            float ax = fabsf(v.x), ay = fabsf(v.y), az = fabsf(v.z), aw = fabsf(v.w);
            float c0 = fmaxf(fmaxf(ax, ay), az);
            float c1 = fmaxf(az, aw);
            float cand = mm == 0 ? c0 : (mm == 1 ? c1 : ax);
            m = fmaxf(m, cand);
        }
    }
    for (int off = 32; off > 0; off >>= 1) m = fmaxf(m, __shfl_down(m, off, 64));
    __shared__ float s[4];
    if ((threadIdx.x & 63) == 0) s[threadIdx.x >> 6] = m;
    __syncthreads();
    if (threadIdx.x == 0) {
        m = fmaxf(fmaxf(s[0], s[1]), fmaxf(s[2], s[3]));
        part[fb] = __float_as_uint(m);          // plain store, no init needed
    }
}

// Pass 2: int32 histogram into 16 XOR-swizzled LDS copies, int64 flush.
// grid (16, B) x 256. LDS = 40960 B -> 4 blocks/CU, no dispatch tail.
__global__ __launch_bounds__(256) void k_bin(const float* __restrict__ x,
                                             const unsigned int* __restrict__ part,
                                             unsigned long long* __restrict__ acc) {
    __shared__ int h[FEAT * CSTRIDE];
    for (int i = threadIdx.x; i < FEAT * CSTRIDE; i += 256) h[i] = 0;
    int b = blockIdx.y;
    // reduce the 16 partial maxes (uint compare == float compare for >=0)
    unsigned int um = 0u;
    #pragma unroll
    for (int p = 0; p < 16; ++p) um = um > part[b * 16 + p] ? um : part[b * 16 + p];
    float bmax = __uint_as_float(um);
    float thick = fmaxf(2.0f * bmax, 1e-5f);
    float inv_thick = 1.0f / thick;
    __syncthreads();

    const float4* base = (const float4*)(x + (size_t)b * NPTS * 6);
    int tid = blockIdx.x * 256 + threadIdx.x;   // 4096 threads per batch
    int k = threadIdx.x & (COPIES - 1);
    #pragma unroll
    for (int it = 0; it < 8; ++it) {
        int i = tid + it * 4096;
        float4 f0 = base[3 * i + 0];
        float4 f1 = base[3 * i + 1];
        float4 f2 = base[3 * i + 2];
        bin_point(h, k, f0.x, f0.y, f0.z, f0.w, f1.x, f1.y, bmax, inv_thick);
        bin_point(h, k, f1.z, f1.w, f2.x, f2.y, f2.z, f2.w, bmax, inv_thick);
    }
    __syncthreads();
    for (int v = threadIdx.x; v < FEAT; v += 256) {
        long long sum = 0;
        #pragma unroll
        for (int c = 0; c < COPIES; ++c) sum += (long long)h[v * CSTRIDE + c];
        atomicAdd(&acc[b * FEAT + v], (unsigned long long)sum); // native int64
    }
}

// Pass 3: features + L2 normalize. grid B x 640 (one thread per feature).
__global__ __launch_bounds__(640) void k_final(const unsigned long long* __restrict__ acc,
                                               float* __restrict__ out) {
    int b = blockIdx.x;
    int t = threadIdx.x;           // 0..639
    int cell = t / 10, j = t - cell * 10;
    long long ni = (long long)acc[b * FEAT + cell * 10];   // exact count
    long long vi = (long long)acc[b * FEAT + t];
    float n = (float)ni;
    float fc = fmaxf(n, 1.0f);
    float up = 1.0f / sqrtf(fc);
    float val;
    if (j == 0)      val = 0.001f * n * up;
    else if (j < 4)  val = ((float)vi * (1.0f / S_OFF)) * up;
    else             val = ((float)vi * (1.0f / S_COV)) / fc;

    __shared__ float red[12];
    float s = val * val;
    for (int off = 32; off > 0; off >>= 1) s += __shfl_down(s, off, 64);
    if ((t & 63) == 0) red[t >> 6] = s;
    __syncthreads();
    if (t == 0) {
        float tot = 0.0f;
        #pragma unroll
        for (int w = 0; w < 10; ++w) tot += red[w];
        red[10] = fmaxf(sqrtf(tot), 1e-12f);
    }
    __syncthreads();
    out[b * FEAT + t] = val / red[10];
}

extern "C" void kernel_launch(void* const* d_in, const int* in_sizes, int n_in,
                              void* d_out, int out_size, void* d_ws, size_t ws_size,
                              hipStream_t stream) {
    const float* x = (const float*)d_in[0];
    float* out = (float*)d_out;
    unsigned int* part = (unsigned int*)d_ws;
    unsigned long long* acc = (unsigned long long*)((char*)d_ws + 4096);

    dim3 grid(16, BATCH);
    k_bbox<<<grid, 256, 0, stream>>>(x, part, acc);
    k_bin<<<grid, 256, 0, stream>>>(x, part, acc);
    k_final<<<BATCH, 640, 0, stream>>>(acc, out);
}